// Round 1
// baseline (404.633 us; speedup 1.0000x reference)
//
#include <hip/hip_runtime.h>

#define NEGV -10000000000.0f

typedef _Float16 half8 __attribute__((ext_vector_type(8)));
typedef float f32x4 __attribute__((ext_vector_type(4)));

// ---------------------------------------------------------------------------
// Kernel 1: W16T[n][k] = (fp16) W_e[k][n]   (1024x1024 transpose+convert)
// ---------------------------------------------------------------------------
__global__ void wconv_kernel(const float* __restrict__ We, _Float16* __restrict__ W16T) {
  __shared__ float tile[32][33];
  const int tx = threadIdx.x, ty = threadIdx.y;
  const int n0 = blockIdx.x * 32, k0 = blockIdx.y * 32;
  tile[ty][tx] = We[(size_t)(k0 + ty) * 1024 + n0 + tx];
  __syncthreads();
  W16T[(size_t)(n0 + ty) * 1024 + k0 + tx] = (_Float16)tile[tx][ty];
}

// ---------------------------------------------------------------------------
// Kernel 2: hpb[b][h] = hidden[b,:] @ W_h[:,h] + b_h[h] + b_e[h]   (fp32)
// ---------------------------------------------------------------------------
__global__ void hproj_kernel(const float* __restrict__ hidden, const float* __restrict__ W_h,
                             const float* __restrict__ b_h, const float* __restrict__ b_e,
                             float* __restrict__ hpb) {
  const int b = blockIdx.x >> 2;
  const int h = ((blockIdx.x & 3) << 8) | threadIdx.x;
  const float* hb = hidden + b * 1024;
  float a0 = 0.f, a1 = 0.f, a2 = 0.f, a3 = 0.f;
  #pragma unroll 4
  for (int k = 0; k < 1024; k += 4) {
    a0 = fmaf(hb[k + 0], W_h[(size_t)(k + 0) * 1024 + h], a0);
    a1 = fmaf(hb[k + 1], W_h[(size_t)(k + 1) * 1024 + h], a1);
    a2 = fmaf(hb[k + 2], W_h[(size_t)(k + 2) * 1024 + h], a2);
    a3 = fmaf(hb[k + 3], W_h[(size_t)(k + 3) * 1024 + h], a3);
  }
  hpb[b * 1024 + h] = b_h[h] + b_e[h] + ((a0 + a1) + (a2 + a3));
}

// ---------------------------------------------------------------------------
// Kernel 3: fused  logits[b,s] = mask ? v . tanh(hpb[b,:] + enc[b,s,:]@W_e) : NEG
// BM=128 rows/block (one b per block), n-loop over 8 N-tiles inside block,
// BK=64, double-buffered LDS, fp16 MFMA 16x16x32, XOR-swizzled LDS tiles.
// 4 waves; wave w owns rows [w*32, w*32+32): mi in {0,1}, ni in 0..7.
// ---------------------------------------------------------------------------
__global__ __launch_bounds__(256, 2) void attn_gemm_kernel(
    const float* __restrict__ enc, const _Float16* __restrict__ W16T,
    const float* __restrict__ hpb, const float* __restrict__ v,
    const int* __restrict__ mask, float* __restrict__ logits) {
  __shared__ __align__(16) _Float16 Alds[2][128 * 64];
  __shared__ __align__(16) _Float16 Blds[2][128 * 64];
  __shared__ float vh_s[1024];
  __shared__ float hp_s[1024];

  const int tid = threadIdx.x;
  const int wid = tid >> 6;
  const int lane = tid & 63;
  const int l15 = lane & 15;
  const int qq = lane >> 4;
  const int m0 = blockIdx.x << 7;   // 128 rows per block
  const int b = m0 >> 11;           // S = 2048 divides into BM=128 tiles

  for (int i = tid; i < 1024; i += 256) {
    vh_s[i] = v[i];
    hp_s[i] = hpb[(b << 10) + i];
  }

  float4 areg[8];
  half8 breg[4];

  // --- staging: A tile = enc[m0..m0+128][kt*64..+64] fp32 -> fp16, swizzled
  auto issueA = [&](int kt) {
    #pragma unroll
    for (int i = 0; i < 4; ++i) {
      const int gd = tid + i * 256;      // 16B-dst granule id (0..1023)
      const int row = gd >> 3;           // 128 rows x 8 granules
      const int g = gd & 7;
      const float* p = enc + (size_t)(m0 + row) * 1024 + kt * 64 + g * 8;
      areg[2 * i + 0] = *(const float4*)p;
      areg[2 * i + 1] = *(const float4*)(p + 4);
    }
  };
  auto writeA = [&](int buf) {
    #pragma unroll
    for (int i = 0; i < 4; ++i) {
      const int gd = tid + i * 256;
      const int row = gd >> 3;
      const int g = gd & 7;
      const float4 x = areg[2 * i + 0], y = areg[2 * i + 1];
      half8 hv;
      hv[0] = (_Float16)x.x; hv[1] = (_Float16)x.y; hv[2] = (_Float16)x.z; hv[3] = (_Float16)x.w;
      hv[4] = (_Float16)y.x; hv[5] = (_Float16)y.y; hv[6] = (_Float16)y.z; hv[7] = (_Float16)y.w;
      const int byte = row * 128 + ((g * 16) ^ ((row & 7) << 4));
      *(half8*)((char*)(&Alds[buf][0]) + byte) = hv;
    }
  };
  // --- staging: B tile = W16T[nt*128..+128][kt*64..+64] (i.e. W_e^T), swizzled
  auto issueB = [&](int nt, int kt) {
    #pragma unroll
    for (int i = 0; i < 4; ++i) {
      const int gd = tid + i * 256;
      const int np = gd >> 3;
      const int gk = gd & 7;
      breg[i] = *(const half8*)(W16T + (size_t)(nt * 128 + np) * 1024 + kt * 64 + gk * 8);
    }
  };
  auto writeB = [&](int buf) {
    #pragma unroll
    for (int i = 0; i < 4; ++i) {
      const int gd = tid + i * 256;
      const int np = gd >> 3;
      const int gk = gd & 7;
      const int byte = np * 128 + ((gk * 16) ^ ((np & 7) << 4));
      *(half8*)((char*)(&Blds[buf][0]) + byte) = breg[i];
    }
  };

  // prologue: stage tile 0 into buffer 0
  issueA(0);
  issueB(0, 0);
  writeA(0);
  writeB(0);

  float rowsum[2][4];
  #pragma unroll
  for (int mi = 0; mi < 2; ++mi) {
    rowsum[mi][0] = 0.f; rowsum[mi][1] = 0.f; rowsum[mi][2] = 0.f; rowsum[mi][3] = 0.f;
  }
  const f32x4 zero4 = {0.f, 0.f, 0.f, 0.f};

  #pragma unroll 1
  for (int nt = 0; nt < 8; ++nt) {
    f32x4 acc[2][8];
    #pragma unroll
    for (int mi = 0; mi < 2; ++mi)
      #pragma unroll
      for (int ni = 0; ni < 8; ++ni) acc[mi][ni] = zero4;

    #pragma unroll 1
    for (int kt = 0; kt < 16; ++kt) {
      const int t = (nt << 4) + kt;
      const int cur = t & 1;
      __syncthreads();  // buf[cur] fully staged by all waves
      const int t1 = t + 1;
      if (t1 < 128) {   // early-issue next tile's global loads (latency hides under MFMA)
        issueA(t1 & 15);
        issueB(t1 >> 4, t1 & 15);
      }
      const char* Ab = (const char*)(&Alds[cur][0]);
      const char* Bb = (const char*)(&Blds[cur][0]);
      const int sw = (l15 & 7) << 4;
      const int rb0 = ((wid << 5) + l15) << 7;  // A row byte base (row*128)
      #pragma unroll
      for (int c = 0; c < 2; ++c) {
        const int gb = ((((c << 2) + qq) << 4)) ^ sw;
        const half8 a0 = *(const half8*)(Ab + rb0 + gb);
        const half8 a1 = *(const half8*)(Ab + rb0 + 2048 + gb);
        #pragma unroll
        for (int ni = 0; ni < 8; ++ni) {
          const half8 bf = *(const half8*)(Bb + ((((ni << 4) + l15) << 7)) + gb);
          acc[0][ni] = __builtin_amdgcn_mfma_f32_16x16x32_f16(a0, bf, acc[0][ni], 0, 0, 0);
          acc[1][ni] = __builtin_amdgcn_mfma_f32_16x16x32_f16(a1, bf, acc[1][ni], 0, 0, 0);
        }
      }
      if (t1 < 128) {   // convert+write next tile into the other buffer
        writeA(cur ^ 1);
        writeB(cur ^ 1);
      }
    }

    // epilogue for this N-tile: rowsum += tanh(acc + hproj + b_e) * v
    const int hbase = nt << 7;
    #pragma unroll
    for (int ni = 0; ni < 8; ++ni) {
      const int h = hbase + (ni << 4) + l15;
      const float hv = hp_s[h];
      const float vv = vh_s[h];
      #pragma unroll
      for (int mi = 0; mi < 2; ++mi)
        #pragma unroll
        for (int r = 0; r < 4; ++r)
          rowsum[mi][r] += tanhf(acc[mi][ni][r] + hv) * vv;
    }
  }

  // reduce over the 16 column-lanes, apply mask, store logits
  #pragma unroll
  for (int mi = 0; mi < 2; ++mi)
    #pragma unroll
    for (int r = 0; r < 4; ++r) {
      float s = rowsum[mi][r];
      s += __shfl_xor(s, 1);
      s += __shfl_xor(s, 2);
      s += __shfl_xor(s, 4);
      s += __shfl_xor(s, 8);
      rowsum[mi][r] = s;
    }
  if (l15 == 0) {
    #pragma unroll
    for (int mi = 0; mi < 2; ++mi)
      #pragma unroll
      for (int r = 0; r < 4; ++r) {
        const int row = (wid << 5) + (mi << 4) + (qq << 2) + r;
        const int m = m0 + row;
        const int s = m & 2047;
        const float lg = (mask[(b << 11) + s] == 0) ? NEGV : rowsum[mi][r];
        logits[m] = lg;
      }
  }
}

// ---------------------------------------------------------------------------
// Kernel 4: softmax over S=2048 per batch row -> attention weights (output 1)
// ---------------------------------------------------------------------------
__global__ void softmax_kernel(const float* __restrict__ logits, float* __restrict__ wout) {
  __shared__ float red[4];
  const int b = blockIdx.x, tid = threadIdx.x;
  const int wid = tid >> 6, lane = tid & 63;
  const float* lb = logits + b * 2048;
  float x[8];
  #pragma unroll
  for (int j = 0; j < 8; ++j) x[j] = lb[tid + j * 256];
  float m = x[0];
  #pragma unroll
  for (int j = 1; j < 8; ++j) m = fmaxf(m, x[j]);
  #pragma unroll
  for (int off = 32; off > 0; off >>= 1) m = fmaxf(m, __shfl_xor(m, off));
  if (lane == 0) red[wid] = m;
  __syncthreads();
  m = fmaxf(fmaxf(red[0], red[1]), fmaxf(red[2], red[3]));
  __syncthreads();
  float e[8];
  float s = 0.f;
  #pragma unroll
  for (int j = 0; j < 8; ++j) { e[j] = expf(x[j] - m); s += e[j]; }
  #pragma unroll
  for (int off = 32; off > 0; off >>= 1) s += __shfl_xor(s, off);
  if (lane == 0) red[wid] = s;
  __syncthreads();
  s = red[0] + red[1] + red[2] + red[3];
  const float inv = 1.0f / s;
  #pragma unroll
  for (int j = 0; j < 8; ++j) wout[b * 2048 + tid + j * 256] = e[j] * inv;
}

// ---------------------------------------------------------------------------
// Kernel 5: context[b,e] = sum_s w[b,s] * enc[b,s,e]   (memory-bound)
// 512 blocks = (b, s-chunk of 128); register accumulate, 4 atomicAdds/thread.
// ---------------------------------------------------------------------------
__global__ void context_kernel(const float* __restrict__ enc, const float* __restrict__ wout,
                               float* __restrict__ ctx) {
  const int b = blockIdx.x >> 4;
  const int ch = blockIdx.x & 15;
  const int tid = threadIdx.x;
  float ax = 0.f, ay = 0.f, az = 0.f, aw = 0.f;
  const int s0 = ch * 128;
  for (int i = 0; i < 128; ++i) {
    const int s = s0 + i;
    const float w = wout[b * 2048 + s];
    const float4 r = *(const float4*)(enc + (size_t)(b * 2048 + s) * 1024 + tid * 4);
    ax = fmaf(w, r.x, ax);
    ay = fmaf(w, r.y, ay);
    az = fmaf(w, r.z, az);
    aw = fmaf(w, r.w, aw);
  }
  float* c = ctx + b * 1024 + tid * 4;
  atomicAdd(c + 0, ax);
  atomicAdd(c + 1, ay);
  atomicAdd(c + 2, az);
  atomicAdd(c + 3, aw);
}

// ---------------------------------------------------------------------------
extern "C" void kernel_launch(void* const* d_in, const int* in_sizes, int n_in,
                              void* d_out, int out_size, void* d_ws, size_t ws_size,
                              hipStream_t stream) {
  const float* hidden = (const float*)d_in[0];
  const float* enc    = (const float*)d_in[1];
  const int*   mask   = (const int*)d_in[2];
  const float* W_h    = (const float*)d_in[3];
  const float* b_h    = (const float*)d_in[4];
  const float* W_e    = (const float*)d_in[5];
  const float* b_e    = (const float*)d_in[6];
  const float* v      = (const float*)d_in[7];

  float* ctx  = (float*)d_out;              // context: 32*1024 floats
  float* wout = (float*)d_out + 32 * 1024;  // attention weights: 32*2048 floats

  char* ws = (char*)d_ws;
  _Float16* W16T = (_Float16*)ws;                                   // 2 MB
  float* hpb     = (float*)(ws + 2 * 1024 * 1024);                  // 128 KB
  float* logits  = (float*)(ws + 2 * 1024 * 1024 + 32 * 1024 * 4);  // 256 KB

  hipMemsetAsync(ctx, 0, 32 * 1024 * sizeof(float), stream);
  hipLaunchKernelGGL(wconv_kernel, dim3(32, 32), dim3(32, 32), 0, stream, W_e, W16T);
  hipLaunchKernelGGL(hproj_kernel, dim3(128), dim3(256), 0, stream, hidden, W_h, b_h, b_e, hpb);
  hipLaunchKernelGGL(attn_gemm_kernel, dim3(512), dim3(256), 0, stream,
                     enc, W16T, hpb, v, mask, logits);
  hipLaunchKernelGGL(softmax_kernel, dim3(32), dim3(256), 0, stream, logits, wout);
  hipLaunchKernelGGL(context_kernel, dim3(512), dim3(256), 0, stream, enc, wout, ctx);
}

// Round 2
// 392.302 us; speedup vs baseline: 1.0314x; 1.0314x over previous
//
#include <hip/hip_runtime.h>

#define NEGV -10000000000.0f

typedef _Float16 half8 __attribute__((ext_vector_type(8)));
typedef float f32x4 __attribute__((ext_vector_type(4)));

__device__ __forceinline__ void gld16(const void* g, void* l) {
  __builtin_amdgcn_global_load_lds((const __attribute__((address_space(1))) void*)g,
                                   (__attribute__((address_space(3))) void*)l,
                                   16, 0, 0);
}

__device__ __forceinline__ float fast_tanh(float x) {
  const float e = __expf(2.0f * x);
  return 1.0f - 2.0f * __builtin_amdgcn_rcpf(e + 1.0f);
}

// ---------------------------------------------------------------------------
// enc fp32 -> fp16 (one pass, memory-bound)
// ---------------------------------------------------------------------------
__global__ void encconv_kernel(const float* __restrict__ enc, _Float16* __restrict__ enc16) {
  const size_t base = ((size_t)blockIdx.x * 256 + threadIdx.x) * 8;
  const float4 x = *(const float4*)(enc + base);
  const float4 y = *(const float4*)(enc + base + 4);
  half8 h;
  h[0] = (_Float16)x.x; h[1] = (_Float16)x.y; h[2] = (_Float16)x.z; h[3] = (_Float16)x.w;
  h[4] = (_Float16)y.x; h[5] = (_Float16)y.y; h[6] = (_Float16)y.z; h[7] = (_Float16)y.w;
  *(half8*)(enc16 + base) = h;
}

// ---------------------------------------------------------------------------
// W16T[n][k] = (fp16) W_e[k][n]   (1024x1024 transpose+convert, LINEAR layout)
// ---------------------------------------------------------------------------
__global__ void wconv_kernel(const float* __restrict__ We, _Float16* __restrict__ W16T) {
  __shared__ float tile[32][33];
  const int tx = threadIdx.x, ty = threadIdx.y;
  const int n0 = blockIdx.x * 32, k0 = blockIdx.y * 32;
  tile[ty][tx] = We[(size_t)(k0 + ty) * 1024 + n0 + tx];
  __syncthreads();
  W16T[(size_t)(n0 + ty) * 1024 + k0 + tx] = (_Float16)tile[tx][ty];
}

// ---------------------------------------------------------------------------
// hpb[b][h] = hidden[b,:] @ W_h[:,h] + b_h[h] + b_e[h]   (fp32)
// ---------------------------------------------------------------------------
__global__ void hproj_kernel(const float* __restrict__ hidden, const float* __restrict__ W_h,
                             const float* __restrict__ b_h, const float* __restrict__ b_e,
                             float* __restrict__ hpb) {
  const int b = blockIdx.x >> 2;
  const int h = ((blockIdx.x & 3) << 8) | threadIdx.x;
  const float* hb = hidden + b * 1024;
  float a0 = 0.f, a1 = 0.f, a2 = 0.f, a3 = 0.f;
  #pragma unroll 4
  for (int k = 0; k < 1024; k += 4) {
    a0 = fmaf(hb[k + 0], W_h[(size_t)(k + 0) * 1024 + h], a0);
    a1 = fmaf(hb[k + 1], W_h[(size_t)(k + 1) * 1024 + h], a1);
    a2 = fmaf(hb[k + 2], W_h[(size_t)(k + 2) * 1024 + h], a2);
    a3 = fmaf(hb[k + 3], W_h[(size_t)(k + 3) * 1024 + h], a3);
  }
  hpb[b * 1024 + h] = b_h[h] + b_e[h] + ((a0 + a1) + (a2 + a3));
}

// ---------------------------------------------------------------------------
// FAST PATH GEMM: logits[b,s] = mask ? v . tanh(hpb[b,:] + enc[b,s,:]@W_e) : NEG
// BM=256 rows/block, 512 threads (8 waves as 4M x 2N), BK=64, BN=128 per nt.
// Triple-buffered LDS, global_load_lds staging (pre-swizzled source),
// counted vmcnt(6) -- loads for tile t+2 stay in flight across barriers.
// ---------------------------------------------------------------------------
__global__ __launch_bounds__(512, 2) void attn_gemm8_kernel(
    const _Float16* __restrict__ enc16, const _Float16* __restrict__ W16T,
    const float* __restrict__ hpb, const float* __restrict__ v,
    const int* __restrict__ mask, float* __restrict__ logits) {
  __shared__ __align__(16) _Float16 Abuf[3][256 * 64];  // 96 KB
  __shared__ __align__(16) _Float16 Bbuf[3][128 * 64];  // 48 KB
  __shared__ float hp_s[1024];
  __shared__ float vh_s[1024];

  const int tid = threadIdx.x;
  const int wid = tid >> 6;
  const int lane = tid & 63;
  const int l15 = lane & 15;
  const int qq = lane >> 4;
  const int wr = wid >> 1;  // 0..3: rows wr*64..+64
  const int wc = wid & 1;   // 0..1: cols wc*64..+64 within the 128-wide nt pass
  const int m0 = blockIdx.x << 8;  // 256 rows per block
  const int b = blockIdx.x >> 3;   // 2048/256 = 8 blocks per batch

  for (int i = tid; i < 1024; i += 512) {
    hp_s[i] = hpb[(b << 10) + i];
    vh_s[i] = v[i];
  }

  const char* encb = (const char*)(enc16 + (size_t)m0 * 1024);

  // A tile: 256 rows x 64 k fp16 = 32 KB = 2048 granules; 4 gld16/thread (2/half)
  auto stageA = [&](int buf, int t, int half) {
    const int kb = (t & 15) << 7;  // byte offset of k-tile within a 2048B row
    char* dstbase = (char*)(&Abuf[buf][0]) + (wid << 10);
    #pragma unroll
    for (int i = 2 * half; i < 2 * half + 2; ++i) {
      const int gd = tid + (i << 9);
      const int row = gd >> 3;
      const int g = gd & 7;
      const int col = kb + ((g << 4) ^ ((row & 7) << 4));  // inverse-swizzled source
      gld16(encb + (size_t)row * 2048 + col, dstbase + (i << 13));
    }
  };
  // B tile: 128 rows x 64 k fp16 = 16 KB = 1024 granules; 2 gld16/thread (1/half)
  auto stageB = [&](int buf, int t, int half) {
    const int nt = t >> 4;
    const int kb = (t & 15) << 7;
    const char* wb = (const char*)(W16T + (size_t)nt * 128 * 1024);
    char* dstbase = (char*)(&Bbuf[buf][0]) + (wid << 10);
    const int i = half;
    const int gd = tid + (i << 9);
    const int np = gd >> 3;
    const int g = gd & 7;
    const int col = kb + ((g << 4) ^ ((np & 7) << 4));
    gld16(wb + (size_t)np * 2048 + col, dstbase + (i << 13));
  };

  f32x4 acc[4][4];
  float rowsum[4][4];
  #pragma unroll
  for (int mi = 0; mi < 4; ++mi)
    #pragma unroll
    for (int j = 0; j < 4; ++j) {
      acc[mi][j] = (f32x4){0.f, 0.f, 0.f, 0.f};
      rowsum[mi][j] = 0.f;
    }

  // prologue: stage tiles 0 and 1 (12 loads), drain once
  stageA(0, 0, 0); stageB(0, 0, 0); stageA(0, 0, 1); stageB(0, 0, 1);
  stageA(1, 1, 0); stageB(1, 1, 0); stageA(1, 1, 1); stageB(1, 1, 1);
  __syncthreads();

  int bi = 0;
  #pragma unroll 1
  for (int t = 0; t < 128; ++t) {
    const int bi2 = (bi >= 1) ? bi - 1 : bi + 2;  // (bi+2)%3
    // ---- phase 1 (k-frag c=0) ----
    if (t < 126) { stageA(bi2, t + 2, 0); stageB(bi2, t + 2, 0); }
    {
      const char* A = (const char*)(&Abuf[bi][0]);
      const char* B = (const char*)(&Bbuf[bi][0]);
      const int gb = qq << 4;
      half8 a[4], bf[4];
      #pragma unroll
      for (int mi = 0; mi < 4; ++mi) {
        const int row = (wr << 6) + (mi << 4) + l15;
        a[mi] = *(const half8*)(A + (row << 7) + (gb ^ ((row & 7) << 4)));
      }
      #pragma unroll
      for (int ni = 0; ni < 4; ++ni) {
        const int np = (wc << 6) + (ni << 4) + l15;
        bf[ni] = *(const half8*)(B + (np << 7) + (gb ^ ((np & 7) << 4)));
      }
      __builtin_amdgcn_s_setprio(1);
      #pragma unroll
      for (int mi = 0; mi < 4; ++mi)
        #pragma unroll
        for (int ni = 0; ni < 4; ++ni)
          acc[mi][ni] = __builtin_amdgcn_mfma_f32_16x16x32_f16(a[mi], bf[ni], acc[mi][ni], 0, 0, 0);
      __builtin_amdgcn_s_setprio(0);
    }
    // ---- phase 2 (k-frag c=1) ----
    if (t < 126) { stageA(bi2, t + 2, 1); stageB(bi2, t + 2, 1); }
    {
      const char* A = (const char*)(&Abuf[bi][0]);
      const char* B = (const char*)(&Bbuf[bi][0]);
      const int gb = (4 + qq) << 4;
      half8 a[4], bf[4];
      #pragma unroll
      for (int mi = 0; mi < 4; ++mi) {
        const int row = (wr << 6) + (mi << 4) + l15;
        a[mi] = *(const half8*)(A + (row << 7) + (gb ^ ((row & 7) << 4)));
      }
      #pragma unroll
      for (int ni = 0; ni < 4; ++ni) {
        const int np = (wc << 6) + (ni << 4) + l15;
        bf[ni] = *(const half8*)(B + (np << 7) + (gb ^ ((np & 7) << 4)));
      }
      __builtin_amdgcn_s_setprio(1);
      #pragma unroll
      for (int mi = 0; mi < 4; ++mi)
        #pragma unroll
        for (int ni = 0; ni < 4; ++ni)
          acc[mi][ni] = __builtin_amdgcn_mfma_f32_16x16x32_f16(a[mi], bf[ni], acc[mi][ni], 0, 0, 0);
      __builtin_amdgcn_s_setprio(0);
    }
    // ---- per-nt epilogue: rowsum += tanh(acc + hproj) * v; reset acc ----
    if ((t & 15) == 15) {
      const int nt = t >> 4;
      const int hb = (nt << 7) + (wc << 6);
      #pragma unroll
      for (int ni = 0; ni < 4; ++ni) {
        const int h = hb + (ni << 4) + l15;
        const float hv = hp_s[h];
        const float vv = vh_s[h];
        #pragma unroll
        for (int mi = 0; mi < 4; ++mi) {
          #pragma unroll
          for (int r = 0; r < 4; ++r)
            rowsum[mi][r] += fast_tanh(acc[mi][ni][r] + hv) * vv;
          acc[mi][ni] = (f32x4){0.f, 0.f, 0.f, 0.f};
        }
      }
    }
    // ---- counted wait: tile t+1 landed for THIS wave; t+2's 6 stay in flight
    if (t < 126) asm volatile("s_waitcnt vmcnt(6)" ::: "memory");
    else         asm volatile("s_waitcnt vmcnt(0)" ::: "memory");
    __builtin_amdgcn_s_barrier();
    bi = (bi >= 2) ? 0 : bi + 1;
  }

  // reduce across the 16 column-lanes of each wave
  #pragma unroll
  for (int mi = 0; mi < 4; ++mi)
    #pragma unroll
    for (int r = 0; r < 4; ++r) {
      float s = rowsum[mi][r];
      s += __shfl_xor(s, 1);
      s += __shfl_xor(s, 2);
      s += __shfl_xor(s, 4);
      s += __shfl_xor(s, 8);
      rowsum[mi][r] = s;
    }
  // cross-wave (wc) reduce through LDS (Abuf is dead now)
  float* red = (float*)(&Abuf[0][0]);
  if (l15 == 0) {
    #pragma unroll
    for (int mi = 0; mi < 4; ++mi)
      #pragma unroll
      for (int r = 0; r < 4; ++r) {
        const int row = (wr << 6) + (mi << 4) + (qq << 2) + r;
        red[(row << 1) + wc] = rowsum[mi][r];
      }
  }
  __syncthreads();
  if (tid < 256) {
    const float s = red[tid << 1] + red[(tid << 1) + 1];
    const int srow = ((blockIdx.x & 7) << 8) + tid;
    logits[m0 + tid] = (mask[(b << 11) + srow] == 0) ? NEGV : s;
  }
}

// ---------------------------------------------------------------------------
// softmax over S=2048 per batch row -> attention weights (output 1)
// ---------------------------------------------------------------------------
__global__ void softmax_kernel(const float* __restrict__ logits, float* __restrict__ wout) {
  __shared__ float red[4];
  const int b = blockIdx.x, tid = threadIdx.x;
  const int wid = tid >> 6, lane = tid & 63;
  const float* lb = logits + b * 2048;
  float x[8];
  #pragma unroll
  for (int j = 0; j < 8; ++j) x[j] = lb[tid + j * 256];
  float m = x[0];
  #pragma unroll
  for (int j = 1; j < 8; ++j) m = fmaxf(m, x[j]);
  #pragma unroll
  for (int off = 32; off > 0; off >>= 1) m = fmaxf(m, __shfl_xor(m, off));
  if (lane == 0) red[wid] = m;
  __syncthreads();
  m = fmaxf(fmaxf(red[0], red[1]), fmaxf(red[2], red[3]));
  __syncthreads();
  float e[8];
  float s = 0.f;
  #pragma unroll
  for (int j = 0; j < 8; ++j) { e[j] = expf(x[j] - m); s += e[j]; }
  #pragma unroll
  for (int off = 32; off > 0; off >>= 1) s += __shfl_xor(s, off);
  if (lane == 0) red[wid] = s;
  __syncthreads();
  s = red[0] + red[1] + red[2] + red[3];
  const float inv = 1.0f / s;
  #pragma unroll
  for (int j = 0; j < 8; ++j) wout[b * 2048 + tid + j * 256] = e[j] * inv;
}

// ---------------------------------------------------------------------------
// context from fp16 enc: ctx[b,e] = sum_s w[b,s] * enc16[b,s,e]
// ---------------------------------------------------------------------------
__global__ void context16_kernel(const _Float16* __restrict__ enc16,
                                 const float* __restrict__ wout, float* __restrict__ ctx) {
  const int b = blockIdx.x >> 4;
  const int ch = blockIdx.x & 15;
  const int tl = threadIdx.x & 127;  // e-granule: 8 cols
  const int sh = threadIdx.x >> 7;   // 0/1: s interleave
  float a[8] = {0.f, 0.f, 0.f, 0.f, 0.f, 0.f, 0.f, 0.f};
  #pragma unroll 1
  for (int i = 0; i < 64; ++i) {
    const int s = (ch << 7) + (i << 1) + sh;
    const float w = wout[(b << 11) + s];
    const half8 r = *(const half8*)(enc16 + (((size_t)(b << 11) + s) << 10) + (tl << 3));
    #pragma unroll
    for (int j = 0; j < 8; ++j) a[j] = fmaf(w, (float)r[j], a[j]);
  }
  float* c = ctx + (b << 10) + (tl << 3);
  #pragma unroll
  for (int j = 0; j < 8; ++j) atomicAdd(c + j, a[j]);
}

// ===========================================================================
// FALLBACK PATH (round-1, known-good) -- used only if ws_size is too small
// ===========================================================================
__global__ __launch_bounds__(256, 2) void attn_gemm_fb_kernel(
    const float* __restrict__ enc, const _Float16* __restrict__ W16T,
    const float* __restrict__ hpb, const float* __restrict__ v,
    const int* __restrict__ mask, float* __restrict__ logits) {
  __shared__ __align__(16) _Float16 Alds[2][128 * 64];
  __shared__ __align__(16) _Float16 Blds[2][128 * 64];
  __shared__ float vh_s[1024];
  __shared__ float hp_s[1024];

  const int tid = threadIdx.x;
  const int wid = tid >> 6;
  const int lane = tid & 63;
  const int l15 = lane & 15;
  const int qq = lane >> 4;
  const int m0 = blockIdx.x << 7;
  const int b = m0 >> 11;

  for (int i = tid; i < 1024; i += 256) {
    vh_s[i] = v[i];
    hp_s[i] = hpb[(b << 10) + i];
  }

  float4 areg[8];
  half8 breg[4];

  auto issueA = [&](int kt) {
    #pragma unroll
    for (int i = 0; i < 4; ++i) {
      const int gd = tid + i * 256;
      const int row = gd >> 3;
      const int g = gd & 7;
      const float* p = enc + (size_t)(m0 + row) * 1024 + kt * 64 + g * 8;
      areg[2 * i + 0] = *(const float4*)p;
      areg[2 * i + 1] = *(const float4*)(p + 4);
    }
  };
  auto writeA = [&](int buf) {
    #pragma unroll
    for (int i = 0; i < 4; ++i) {
      const int gd = tid + i * 256;
      const int row = gd >> 3;
      const int g = gd & 7;
      const float4 x = areg[2 * i + 0], y = areg[2 * i + 1];
      half8 hv;
      hv[0] = (_Float16)x.x; hv[1] = (_Float16)x.y; hv[2] = (_Float16)x.z; hv[3] = (_Float16)x.w;
      hv[4] = (_Float16)y.x; hv[5] = (_Float16)y.y; hv[6] = (_Float16)y.z; hv[7] = (_Float16)y.w;
      const int byte = row * 128 + ((g * 16) ^ ((row & 7) << 4));
      *(half8*)((char*)(&Alds[buf][0]) + byte) = hv;
    }
  };
  auto issueB = [&](int nt, int kt) {
    #pragma unroll
    for (int i = 0; i < 4; ++i) {
      const int gd = tid + i * 256;
      const int np = gd >> 3;
      const int gk = gd & 7;
      breg[i] = *(const half8*)(W16T + (size_t)(nt * 128 + np) * 1024 + kt * 64 + gk * 8);
    }
  };
  auto writeB = [&](int buf) {
    #pragma unroll
    for (int i = 0; i < 4; ++i) {
      const int gd = tid + i * 256;
      const int np = gd >> 3;
      const int gk = gd & 7;
      const int byte = np * 128 + ((gk * 16) ^ ((np & 7) << 4));
      *(half8*)((char*)(&Blds[buf][0]) + byte) = breg[i];
    }
  };

  issueA(0);
  issueB(0, 0);
  writeA(0);
  writeB(0);

  float rowsum[2][4];
  #pragma unroll
  for (int mi = 0; mi < 2; ++mi) {
    rowsum[mi][0] = 0.f; rowsum[mi][1] = 0.f; rowsum[mi][2] = 0.f; rowsum[mi][3] = 0.f;
  }
  const f32x4 zero4 = {0.f, 0.f, 0.f, 0.f};

  #pragma unroll 1
  for (int nt = 0; nt < 8; ++nt) {
    f32x4 acc[2][8];
    #pragma unroll
    for (int mi = 0; mi < 2; ++mi)
      #pragma unroll
      for (int ni = 0; ni < 8; ++ni) acc[mi][ni] = zero4;

    #pragma unroll 1
    for (int kt = 0; kt < 16; ++kt) {
      const int t = (nt << 4) + kt;
      const int cur = t & 1;
      __syncthreads();
      const int t1 = t + 1;
      if (t1 < 128) {
        issueA(t1 & 15);
        issueB(t1 >> 4, t1 & 15);
      }
      const char* Ab = (const char*)(&Alds[cur][0]);
      const char* Bb = (const char*)(&Blds[cur][0]);
      const int sw = (l15 & 7) << 4;
      const int rb0 = ((wid << 5) + l15) << 7;
      #pragma unroll
      for (int c = 0; c < 2; ++c) {
        const int gb = ((((c << 2) + qq) << 4)) ^ sw;
        const half8 a0 = *(const half8*)(Ab + rb0 + gb);
        const half8 a1 = *(const half8*)(Ab + rb0 + 2048 + gb);
        #pragma unroll
        for (int ni = 0; ni < 8; ++ni) {
          const half8 bf = *(const half8*)(Bb + ((((ni << 4) + l15) << 7)) + gb);
          acc[0][ni] = __builtin_amdgcn_mfma_f32_16x16x32_f16(a0, bf, acc[0][ni], 0, 0, 0);
          acc[1][ni] = __builtin_amdgcn_mfma_f32_16x16x32_f16(a1, bf, acc[1][ni], 0, 0, 0);
        }
      }
      if (t1 < 128) {
        writeA(cur ^ 1);
        writeB(cur ^ 1);
      }
    }

    const int hbase = nt << 7;
    #pragma unroll
    for (int ni = 0; ni < 8; ++ni) {
      const int h = hbase + (ni << 4) + l15;
      const float hv = hp_s[h];
      const float vv = vh_s[h];
      #pragma unroll
      for (int mi = 0; mi < 2; ++mi)
        #pragma unroll
        for (int r = 0; r < 4; ++r)
          rowsum[mi][r] += tanhf(acc[mi][ni][r] + hv) * vv;
    }
  }

  #pragma unroll
  for (int mi = 0; mi < 2; ++mi)
    #pragma unroll
    for (int r = 0; r < 4; ++r) {
      float s = rowsum[mi][r];
      s += __shfl_xor(s, 1);
      s += __shfl_xor(s, 2);
      s += __shfl_xor(s, 4);
      s += __shfl_xor(s, 8);
      rowsum[mi][r] = s;
    }
  if (l15 == 0) {
    #pragma unroll
    for (int mi = 0; mi < 2; ++mi)
      #pragma unroll
      for (int r = 0; r < 4; ++r) {
        const int row = (wid << 5) + (mi << 4) + (qq << 2) + r;
        const int m = m0 + row;
        const int s = m & 2047;
        const float lg = (mask[(b << 11) + s] == 0) ? NEGV : rowsum[mi][r];
        logits[m] = lg;
      }
  }
}

__global__ void context_fb_kernel(const float* __restrict__ enc, const float* __restrict__ wout,
                                  float* __restrict__ ctx) {
  const int b = blockIdx.x >> 4;
  const int ch = blockIdx.x & 15;
  const int tid = threadIdx.x;
  float ax = 0.f, ay = 0.f, az = 0.f, aw = 0.f;
  const int s0 = ch * 128;
  for (int i = 0; i < 128; ++i) {
    const int s = s0 + i;
    const float w = wout[b * 2048 + s];
    const float4 r = *(const float4*)(enc + (size_t)(b * 2048 + s) * 1024 + tid * 4);
    ax = fmaf(w, r.x, ax);
    ay = fmaf(w, r.y, ay);
    az = fmaf(w, r.z, az);
    aw = fmaf(w, r.w, aw);
  }
  float* c = ctx + b * 1024 + tid * 4;
  atomicAdd(c + 0, ax);
  atomicAdd(c + 1, ay);
  atomicAdd(c + 2, az);
  atomicAdd(c + 3, aw);
}

// ---------------------------------------------------------------------------
extern "C" void kernel_launch(void* const* d_in, const int* in_sizes, int n_in,
                              void* d_out, int out_size, void* d_ws, size_t ws_size,
                              hipStream_t stream) {
  const float* hidden = (const float*)d_in[0];
  const float* enc    = (const float*)d_in[1];
  const int*   mask   = (const int*)d_in[2];
  const float* W_h    = (const float*)d_in[3];
  const float* b_h    = (const float*)d_in[4];
  const float* W_e    = (const float*)d_in[5];
  const float* b_e    = (const float*)d_in[6];
  const float* v      = (const float*)d_in[7];

  float* ctx  = (float*)d_out;              // context: 32*1024 floats
  float* wout = (float*)d_out + 32 * 1024;  // attention weights: 32*2048 floats

  char* ws = (char*)d_ws;
  const size_t ENC16_BYTES = 134217728ULL;  // 32*2048*1024 fp16
  const size_t NEED = ENC16_BYTES + 2097152 + 131072 + 262144;

  hipMemsetAsync(ctx, 0, 32 * 1024 * sizeof(float), stream);

  if (ws_size >= NEED) {
    _Float16* enc16 = (_Float16*)ws;
    _Float16* W16T  = (_Float16*)(ws + ENC16_BYTES);
    float* hpb      = (float*)(ws + ENC16_BYTES + 2097152);
    float* logits   = (float*)(ws + ENC16_BYTES + 2097152 + 131072);

    hipLaunchKernelGGL(encconv_kernel, dim3(32768), dim3(256), 0, stream, enc, enc16);
    hipLaunchKernelGGL(wconv_kernel, dim3(32, 32), dim3(32, 32), 0, stream, W_e, W16T);
    hipLaunchKernelGGL(hproj_kernel, dim3(128), dim3(256), 0, stream, hidden, W_h, b_h, b_e, hpb);
    hipLaunchKernelGGL(attn_gemm8_kernel, dim3(256), dim3(512), 0, stream,
                       enc16, W16T, hpb, v, mask, logits);
    hipLaunchKernelGGL(softmax_kernel, dim3(32), dim3(256), 0, stream, logits, wout);
    hipLaunchKernelGGL(context16_kernel, dim3(512), dim3(256), 0, stream, enc16, wout, ctx);
  } else {
    _Float16* W16T = (_Float16*)ws;                                   // 2 MB
    float* hpb     = (float*)(ws + 2 * 1024 * 1024);                  // 128 KB
    float* logits  = (float*)(ws + 2 * 1024 * 1024 + 32 * 1024 * 4);  // 256 KB

    hipLaunchKernelGGL(wconv_kernel, dim3(32, 32), dim3(32, 32), 0, stream, W_e, W16T);
    hipLaunchKernelGGL(hproj_kernel, dim3(128), dim3(256), 0, stream, hidden, W_h, b_h, b_e, hpb);
    hipLaunchKernelGGL(attn_gemm_fb_kernel, dim3(512), dim3(256), 0, stream,
                       enc, W16T, hpb, v, mask, logits);
    hipLaunchKernelGGL(softmax_kernel, dim3(32), dim3(256), 0, stream, logits, wout);
    hipLaunchKernelGGL(context_fb_kernel, dim3(512), dim3(256), 0, stream, enc, wout, ctx);
  }
}

// Round 3
// 311.122 us; speedup vs baseline: 1.3006x; 1.2609x over previous
//
#include <hip/hip_runtime.h>

#define NEGV -10000000000.0f

typedef _Float16 half8 __attribute__((ext_vector_type(8)));
typedef float f32x4 __attribute__((ext_vector_type(4)));

__device__ __forceinline__ void gld16(const void* g, void* l) {
  __builtin_amdgcn_global_load_lds((const __attribute__((address_space(1))) void*)g,
                                   (__attribute__((address_space(3))) void*)l,
                                   16, 0, 0);
}

__device__ __forceinline__ float fast_tanh(float x) {
  const float e = __expf(2.0f * x);
  return 1.0f - 2.0f * __builtin_amdgcn_rcpf(e + 1.0f);
}

// ---------------------------------------------------------------------------
// enc fp32 -> fp16 (one pass, memory-bound)
// ---------------------------------------------------------------------------
__global__ void encconv_kernel(const float* __restrict__ enc, _Float16* __restrict__ enc16) {
  const size_t base = ((size_t)blockIdx.x * 256 + threadIdx.x) * 8;
  const float4 x = *(const float4*)(enc + base);
  const float4 y = *(const float4*)(enc + base + 4);
  half8 h;
  h[0] = (_Float16)x.x; h[1] = (_Float16)x.y; h[2] = (_Float16)x.z; h[3] = (_Float16)x.w;
  h[4] = (_Float16)y.x; h[5] = (_Float16)y.y; h[6] = (_Float16)y.z; h[7] = (_Float16)y.w;
  *(half8*)(enc16 + base) = h;
}

// ---------------------------------------------------------------------------
// W16T[n][k] = (fp16) W_e[k][n]   (1024x1024 transpose+convert, LINEAR layout)
// ---------------------------------------------------------------------------
__global__ void wconv_kernel(const float* __restrict__ We, _Float16* __restrict__ W16T) {
  __shared__ float tile[32][33];
  const int tx = threadIdx.x, ty = threadIdx.y;
  const int n0 = blockIdx.x * 32, k0 = blockIdx.y * 32;
  tile[ty][tx] = We[(size_t)(k0 + ty) * 1024 + n0 + tx];
  __syncthreads();
  W16T[(size_t)(n0 + ty) * 1024 + k0 + tx] = (_Float16)tile[tx][ty];
}

// ---------------------------------------------------------------------------
// hpb[b][h] = hidden[b,:] @ W_h[:,h] + b_h[h] + b_e[h]   (fp32)
// ---------------------------------------------------------------------------
__global__ void hproj_kernel(const float* __restrict__ hidden, const float* __restrict__ W_h,
                             const float* __restrict__ b_h, const float* __restrict__ b_e,
                             float* __restrict__ hpb) {
  const int b = blockIdx.x >> 2;
  const int h = ((blockIdx.x & 3) << 8) | threadIdx.x;
  const float* hb = hidden + b * 1024;
  float a0 = 0.f, a1 = 0.f, a2 = 0.f, a3 = 0.f;
  #pragma unroll 4
  for (int k = 0; k < 1024; k += 4) {
    a0 = fmaf(hb[k + 0], W_h[(size_t)(k + 0) * 1024 + h], a0);
    a1 = fmaf(hb[k + 1], W_h[(size_t)(k + 1) * 1024 + h], a1);
    a2 = fmaf(hb[k + 2], W_h[(size_t)(k + 2) * 1024 + h], a2);
    a3 = fmaf(hb[k + 3], W_h[(size_t)(k + 3) * 1024 + h], a3);
  }
  hpb[b * 1024 + h] = b_h[h] + b_e[h] + ((a0 + a1) + (a2 + a3));
}

// ---------------------------------------------------------------------------
// FUSED GEMM (m201-style 2-phase/K-tile, counted vmcnt):
//   logits[b,s] = mask ? v . tanh(hpb[b,:] + enc[b,s,:]@W_e) : NEG
// BM=256, BN=256 (4 nt passes over H=1024), BK=32, 512 threads.
// 8 waves as 2M x 4N; per-wave output 128x64 -> acc[8][4] f32x4 (128 VGPR).
// Triple-buffered 16KB A/B tiles; 4 gld_lds per thread per K-tile;
// s_waitcnt vmcnt(4) at tile end (t+2's loads stay in flight, never drain).
// LDS rows are 64B (4 granules); XOR-swizzle with (row>>2)&3 (bit0/1 would
// 4-way-alias within a 16-lane read quarter; bit2/3 gives free 2-way).
// ---------------------------------------------------------------------------
__global__ __launch_bounds__(512, 2) void attn_gemm8_kernel(
    const _Float16* __restrict__ enc16, const _Float16* __restrict__ W16T,
    const float* __restrict__ hpb, const float* __restrict__ v,
    const int* __restrict__ mask, float* __restrict__ logits) {
  __shared__ __align__(16) _Float16 Abuf[3][256 * 32];  // 48 KB
  __shared__ __align__(16) _Float16 Bbuf[3][256 * 32];  // 48 KB
  __shared__ float hp_s[1024];
  __shared__ float vh_s[1024];
  __shared__ float red[256 * 4];

  const int tid = threadIdx.x;
  const int wid = tid >> 6;
  const int lane = tid & 63;
  const int l15 = lane & 15;
  const int qq = lane >> 4;        // 0..3: k-granule of the fragment
  const int wr = wid >> 2;         // 0..1: wave rows [wr*128, +128)
  const int wc = wid & 3;          // 0..3: wave cols [wc*64, +64) within the nt pass
  const int m0 = blockIdx.x << 8;  // 256 rows per block
  const int b = blockIdx.x >> 3;   // 8 blocks per batch

  for (int i = tid; i < 1024; i += 512) {
    hp_s[i] = hpb[(b << 10) + i];
    vh_s[i] = v[i];
  }

  const char* encb = (const char*)(enc16 + (size_t)m0 * 1024);
  const char* wbase = (const char*)W16T;

  // A tile: 256 rows x 32 k fp16 = 16 KB = 1024 granules; 2 gld16/thread
  auto stageA = [&](int buf, int t) {
    const int kb = (t & 31) << 6;  // k-tile byte offset within the 2048B row
    char* db = (char*)(&Abuf[buf][0]) + (wid << 10);
    #pragma unroll
    for (int i = 0; i < 2; ++i) {
      const int gd = tid + (i << 9);
      const int row = gd >> 2;
      const int g = gd & 3;
      const int col = kb + ((g ^ ((row >> 2) & 3)) << 4);  // inverse-swizzled source
      gld16(encb + (size_t)row * 2048 + col, db + (i << 13));
    }
  };
  // B tile: 256 n-rows x 32 k fp16 = 16 KB; nt panel selected by t>>5
  auto stageB = [&](int buf, int t) {
    const int kb = (t & 31) << 6;
    const char* wb = wbase + (size_t)(t >> 5) * 256 * 2048;
    char* db = (char*)(&Bbuf[buf][0]) + (wid << 10);
    #pragma unroll
    for (int i = 0; i < 2; ++i) {
      const int gd = tid + (i << 9);
      const int np = gd >> 2;
      const int g = gd & 3;
      const int col = kb + ((g ^ ((np >> 2) & 3)) << 4);
      gld16(wb + (size_t)np * 2048 + col, db + (i << 13));
    }
  };

  f32x4 acc[8][4];
  float rowsum[8][4];
  #pragma unroll
  for (int mi = 0; mi < 8; ++mi)
    #pragma unroll
    for (int j = 0; j < 4; ++j) {
      acc[mi][j] = (f32x4){0.f, 0.f, 0.f, 0.f};
      rowsum[mi][j] = 0.f;
    }

  // prologue: stage tiles 0,1 into buffers 0,1; full drain once (cheap, safe)
  stageA(0, 0); stageB(0, 0);
  stageA(1, 1); stageB(1, 1);
  __syncthreads();

  const int swz = (qq ^ (l15 >> 2)) << 4;  // lane-constant read swizzle
  int bi = 0;
  #pragma unroll 1
  for (int t = 0; t < 128; ++t) {
    const int bi2 = (bi >= 1) ? bi - 1 : bi + 2;  // (bi+2)%3
    const char* A = (const char*)(&Abuf[bi][0]);
    const char* B = (const char*)(&Bbuf[bi][0]);
    half8 a[4], bf[4];

    // ======== phase 0: C-quadrant mh=0 ========
    #pragma unroll
    for (int mi = 0; mi < 4; ++mi) {
      const int row = (wr << 7) + (mi << 4) + l15;
      a[mi] = *(const half8*)(A + (row << 6) + swz);
    }
    #pragma unroll
    for (int ni = 0; ni < 4; ++ni) {
      const int np = (wc << 6) + (ni << 4) + l15;
      bf[ni] = *(const half8*)(B + (np << 6) + swz);
    }
    if (t < 126) stageA(bi2, t + 2);
    __builtin_amdgcn_s_barrier();
    asm volatile("s_waitcnt lgkmcnt(0)" ::: "memory");
    __builtin_amdgcn_s_setprio(1);
    #pragma unroll
    for (int mi = 0; mi < 4; ++mi)
      #pragma unroll
      for (int ni = 0; ni < 4; ++ni)
        acc[mi][ni] = __builtin_amdgcn_mfma_f32_16x16x32_f16(a[mi], bf[ni], acc[mi][ni], 0, 0, 0);
    __builtin_amdgcn_s_setprio(0);
    __builtin_amdgcn_s_barrier();

    // ======== phase 1: C-quadrant mh=1 (reuses bf) ========
    #pragma unroll
    for (int mi = 0; mi < 4; ++mi) {
      const int row = (wr << 7) + 64 + (mi << 4) + l15;
      a[mi] = *(const half8*)(A + (row << 6) + swz);
    }
    if (t < 126) stageB(bi2, t + 2);
    __builtin_amdgcn_s_barrier();
    asm volatile("s_waitcnt lgkmcnt(0)" ::: "memory");
    __builtin_amdgcn_s_setprio(1);
    #pragma unroll
    for (int mi = 0; mi < 4; ++mi)
      #pragma unroll
      for (int ni = 0; ni < 4; ++ni)
        acc[4 + mi][ni] = __builtin_amdgcn_mfma_f32_16x16x32_f16(a[mi], bf[ni], acc[4 + mi][ni], 0, 0, 0);
    __builtin_amdgcn_s_setprio(0);

    // ---- tile end: counted wait (t+1 landed; t+2's 4 stay in flight) ----
    if (t < 126) asm volatile("s_waitcnt vmcnt(4)" ::: "memory");
    else         asm volatile("s_waitcnt vmcnt(0)" ::: "memory");
    __builtin_amdgcn_s_barrier();

    // ---- per-nt-pass epilogue: rowsum += tanh(acc + hproj) * v ----
    if ((t & 31) == 31) {
      const int nt = t >> 5;
      const int hb = (nt << 8) + (wc << 6);
      #pragma unroll
      for (int ni = 0; ni < 4; ++ni) {
        const int h = hb + (ni << 4) + l15;
        const float hv = hp_s[h];
        const float vv = vh_s[h];
        #pragma unroll
        for (int mi = 0; mi < 8; ++mi) {
          #pragma unroll
          for (int r = 0; r < 4; ++r)
            rowsum[mi][r] += fast_tanh(acc[mi][ni][r] + hv) * vv;
          acc[mi][ni] = (f32x4){0.f, 0.f, 0.f, 0.f};
        }
      }
    }
    bi = (bi >= 2) ? 0 : bi + 1;
  }

  // reduce across the 16 column-lanes of each wave
  #pragma unroll
  for (int mi = 0; mi < 8; ++mi)
    #pragma unroll
    for (int r = 0; r < 4; ++r) {
      float s = rowsum[mi][r];
      s += __shfl_xor(s, 1);
      s += __shfl_xor(s, 2);
      s += __shfl_xor(s, 4);
      s += __shfl_xor(s, 8);
      rowsum[mi][r] = s;
    }
  __syncthreads();
  if (l15 == 0) {
    #pragma unroll
    for (int mi = 0; mi < 8; ++mi)
      #pragma unroll
      for (int r = 0; r < 4; ++r) {
        const int row = (wr << 7) + (mi << 4) + (qq << 2) + r;
        red[(row << 2) + wc] = rowsum[mi][r];
      }
  }
  __syncthreads();
  if (tid < 256) {
    const float s = red[tid << 2] + red[(tid << 2) + 1] + red[(tid << 2) + 2] + red[(tid << 2) + 3];
    const int m = m0 + tid;
    logits[m] = (mask[(b << 11) + (m & 2047)] == 0) ? NEGV : s;
  }
}

// ---------------------------------------------------------------------------
// softmax over S=2048 per batch row -> attention weights (output 1)
// ---------------------------------------------------------------------------
__global__ void softmax_kernel(const float* __restrict__ logits, float* __restrict__ wout) {
  __shared__ float red[4];
  const int b = blockIdx.x, tid = threadIdx.x;
  const int wid = tid >> 6, lane = tid & 63;
  const float* lb = logits + b * 2048;
  float x[8];
  #pragma unroll
  for (int j = 0; j < 8; ++j) x[j] = lb[tid + j * 256];
  float m = x[0];
  #pragma unroll
  for (int j = 1; j < 8; ++j) m = fmaxf(m, x[j]);
  #pragma unroll
  for (int off = 32; off > 0; off >>= 1) m = fmaxf(m, __shfl_xor(m, off));
  if (lane == 0) red[wid] = m;
  __syncthreads();
  m = fmaxf(fmaxf(red[0], red[1]), fmaxf(red[2], red[3]));
  __syncthreads();
  float e[8];
  float s = 0.f;
  #pragma unroll
  for (int j = 0; j < 8; ++j) { e[j] = expf(x[j] - m); s += e[j]; }
  #pragma unroll
  for (int off = 32; off > 0; off >>= 1) s += __shfl_xor(s, off);
  if (lane == 0) red[wid] = s;
  __syncthreads();
  s = red[0] + red[1] + red[2] + red[3];
  const float inv = 1.0f / s;
  #pragma unroll
  for (int j = 0; j < 8; ++j) wout[b * 2048 + tid + j * 256] = e[j] * inv;
}

// ---------------------------------------------------------------------------
// context from fp16 enc: ctx[b,e] = sum_s w[b,s] * enc16[b,s,e]
// ---------------------------------------------------------------------------
__global__ void context16_kernel(const _Float16* __restrict__ enc16,
                                 const float* __restrict__ wout, float* __restrict__ ctx) {
  const int b = blockIdx.x >> 4;
  const int ch = blockIdx.x & 15;
  const int tl = threadIdx.x & 127;  // e-granule: 8 cols
  const int sh = threadIdx.x >> 7;   // 0/1: s interleave
  float a[8] = {0.f, 0.f, 0.f, 0.f, 0.f, 0.f, 0.f, 0.f};
  #pragma unroll 1
  for (int i = 0; i < 64; ++i) {
    const int s = (ch << 7) + (i << 1) + sh;
    const float w = wout[(b << 11) + s];
    const half8 r = *(const half8*)(enc16 + (((size_t)(b << 11) + s) << 10) + (tl << 3));
    #pragma unroll
    for (int j = 0; j < 8; ++j) a[j] = fmaf(w, (float)r[j], a[j]);
  }
  float* c = ctx + (b << 10) + (tl << 3);
  #pragma unroll
  for (int j = 0; j < 8; ++j) atomicAdd(c + j, a[j]);
}

// ---------------------------------------------------------------------------
extern "C" void kernel_launch(void* const* d_in, const int* in_sizes, int n_in,
                              void* d_out, int out_size, void* d_ws, size_t ws_size,
                              hipStream_t stream) {
  const float* hidden = (const float*)d_in[0];
  const float* enc    = (const float*)d_in[1];
  const int*   mask   = (const int*)d_in[2];
  const float* W_h    = (const float*)d_in[3];
  const float* b_h    = (const float*)d_in[4];
  const float* W_e    = (const float*)d_in[5];
  const float* b_e    = (const float*)d_in[6];
  const float* v      = (const float*)d_in[7];

  float* ctx  = (float*)d_out;              // context: 32*1024 floats
  float* wout = (float*)d_out + 32 * 1024;  // attention weights: 32*2048 floats

  char* ws = (char*)d_ws;
  const size_t ENC16_BYTES = 134217728ULL;  // 32*2048*1024 fp16
  _Float16* enc16 = (_Float16*)ws;
  _Float16* W16T  = (_Float16*)(ws + ENC16_BYTES);
  float* hpb      = (float*)(ws + ENC16_BYTES + 2097152);
  float* logits   = (float*)(ws + ENC16_BYTES + 2097152 + 131072);

  hipMemsetAsync(ctx, 0, 32 * 1024 * sizeof(float), stream);
  hipLaunchKernelGGL(encconv_kernel, dim3(32768), dim3(256), 0, stream, enc, enc16);
  hipLaunchKernelGGL(wconv_kernel, dim3(32, 32), dim3(32, 32), 0, stream, W_e, W16T);
  hipLaunchKernelGGL(hproj_kernel, dim3(128), dim3(256), 0, stream, hidden, W_h, b_h, b_e, hpb);
  hipLaunchKernelGGL(attn_gemm8_kernel, dim3(256), dim3(512), 0, stream,
                     enc16, W16T, hpb, v, mask, logits);
  hipLaunchKernelGGL(softmax_kernel, dim3(32), dim3(256), 0, stream, logits, wout);
  hipLaunchKernelGGL(context16_kernel, dim3(512), dim3(256), 0, stream, enc16, wout, ctx);
}